// Round 1
// baseline (2291.492 us; speedup 1.0000x reference)
//
#include <hip/hip_runtime.h>

#define N_NODES 50000
#define N_EDGES 1600000
#define R_REL 4
#define F_IN 32
#define H1 32
#define H2 64
#define NC 3
#define G_BATCH 64

// ---------------- count + inverse-count ----------------
__global__ __launch_bounds__(256) void count_kernel(const int* __restrict__ etype,
                                                    const int* __restrict__ dstp,
                                                    int* __restrict__ cnt) {
    int e = blockIdx.x * 256 + threadIdx.x;
    if (e < N_EDGES) {
        atomicAdd(&cnt[etype[e] * N_NODES + dstp[e]], 1);
    }
}

__global__ __launch_bounds__(256) void invcnt_kernel(const int* __restrict__ cnt,
                                                     float* __restrict__ inv) {
    int i = blockIdx.x * 256 + threadIdx.x;
    if (i < R_REL * N_NODES) {
        int c = cnt[i];
        inv[i] = 1.0f / (float)(c > 1 ? c : 1);
    }
}

// ---------------- layer-1 dense transform ----------------
// out1[n][c] = b1[c] + sum_i x[n][i]*W_root[i][c]
// h_all[r][n][c] = sum_i x[n][i]*W_rel[r][i][c]
__global__ __launch_bounds__(256) void transform1_kernel(
    const float* __restrict__ x, const float* __restrict__ W_rel,
    const float* __restrict__ W_root, const float* __restrict__ b,
    float* __restrict__ out1, float* __restrict__ h_all) {
    __shared__ float sW[5 * F_IN * H1];   // rel 0..3, then root at k=4
    __shared__ float sb[H1];
    __shared__ float sx[8][F_IN];
    for (int i = threadIdx.x; i < 4 * F_IN * H1; i += 256) sW[i] = W_rel[i];
    for (int i = threadIdx.x; i < F_IN * H1; i += 256) sW[4 * F_IN * H1 + i] = W_root[i];
    if (threadIdx.x < H1) sb[threadIdx.x] = b[threadIdx.x];

    int node0 = blockIdx.x * 8;
    {
        int r = threadIdx.x >> 5, c = threadIdx.x & 31;   // 8 rows x 32
        int n = node0 + r;
        sx[r][c] = (n < N_NODES) ? x[n * F_IN + c] : 0.0f;
    }
    __syncthreads();

    int lr = threadIdx.x >> 5;
    int col = threadIdx.x & 31;
    int n = node0 + lr;
    if (n >= N_NODES) return;

    float acc[5];
#pragma unroll
    for (int k = 0; k < 5; ++k) acc[k] = 0.0f;
#pragma unroll
    for (int i = 0; i < F_IN; ++i) {
        float xv = sx[lr][i];
#pragma unroll
        for (int k = 0; k < 5; ++k)
            acc[k] = fmaf(xv, sW[k * F_IN * H1 + i * H1 + col], acc[k]);
    }
#pragma unroll
    for (int r = 0; r < R_REL; ++r)
        h_all[((size_t)r * N_NODES + n) * H1 + col] = acc[r];
    out1[n * H1 + col] = acc[4] + sb[col];
}

// ---------------- layer-1 scatter ----------------
// 8 threads per edge, each does 4 columns (float4 read, 4 scalar atomics)
__global__ __launch_bounds__(256) void scatter1_kernel(
    const int* __restrict__ srcp, const int* __restrict__ dstp,
    const int* __restrict__ etype, const float* __restrict__ inv,
    const float* __restrict__ h_all, float* __restrict__ out1) {
    int t = blockIdx.x * 256 + threadIdx.x;
    int e = t >> 3;
    int q = t & 7;
    if (e >= N_EDGES) return;
    int r = etype[e], s = srcp[e], d = dstp[e];
    float sc = inv[r * N_NODES + d];
    float4 v = *reinterpret_cast<const float4*>(
        &h_all[((size_t)r * N_NODES + s) * H1 + q * 4]);
    float* o = &out1[d * H1 + q * 4];
    atomicAdd(o + 0, v.x * sc);
    atomicAdd(o + 1, v.y * sc);
    atomicAdd(o + 2, v.z * sc);
    atomicAdd(o + 3, v.w * sc);
}

// ---------------- layer-2 dense transform (fused input ReLU) ----------------
__global__ __launch_bounds__(256) void transform2_kernel(
    const float* __restrict__ in1, const float* __restrict__ W_rel,
    const float* __restrict__ W_root, const float* __restrict__ b,
    float* __restrict__ out2, float* __restrict__ h_all) {
    __shared__ float sW[5 * H1 * H2];   // 10240 floats = 40 KiB
    __shared__ float sb[H2];
    __shared__ float sx[4][H1];
    for (int i = threadIdx.x; i < 4 * H1 * H2; i += 256) sW[i] = W_rel[i];
    for (int i = threadIdx.x; i < H1 * H2; i += 256) sW[4 * H1 * H2 + i] = W_root[i];
    if (threadIdx.x < H2) sb[threadIdx.x] = b[threadIdx.x];

    int node0 = blockIdx.x * 4;
    if (threadIdx.x < 128) {
        int r = threadIdx.x >> 5, c = threadIdx.x & 31;  // 4 rows x 32
        int n = node0 + r;
        sx[r][c] = (n < N_NODES) ? fmaxf(in1[n * H1 + c], 0.0f) : 0.0f;
    }
    __syncthreads();

    int lr = threadIdx.x >> 6;        // 4 nodes x 64 lanes
    int col = threadIdx.x & 63;
    int n = node0 + lr;
    if (n >= N_NODES) return;

    float acc[5];
#pragma unroll
    for (int k = 0; k < 5; ++k) acc[k] = 0.0f;
#pragma unroll
    for (int i = 0; i < H1; ++i) {
        float xv = sx[lr][i];
#pragma unroll
        for (int k = 0; k < 5; ++k)
            acc[k] = fmaf(xv, sW[k * H1 * H2 + i * H2 + col], acc[k]);
    }
#pragma unroll
    for (int r = 0; r < R_REL; ++r)
        h_all[((size_t)r * N_NODES + n) * H2 + col] = acc[r];
    out2[n * H2 + col] = acc[4] + sb[col];
}

// ---------------- layer-2 scatter ----------------
// 16 threads per edge, each does 4 of 64 columns
__global__ __launch_bounds__(256) void scatter2_kernel(
    const int* __restrict__ srcp, const int* __restrict__ dstp,
    const int* __restrict__ etype, const float* __restrict__ inv,
    const float* __restrict__ h_all, float* __restrict__ out2) {
    int t = blockIdx.x * 256 + threadIdx.x;
    int e = t >> 4;
    int q = t & 15;
    if (e >= N_EDGES) return;
    int r = etype[e], s = srcp[e], d = dstp[e];
    float sc = inv[r * N_NODES + d];
    float4 v = *reinterpret_cast<const float4*>(
        &h_all[((size_t)r * N_NODES + s) * H2 + q * 4]);
    float* o = &out2[d * H2 + q * 4];
    atomicAdd(o + 0, v.x * sc);
    atomicAdd(o + 1, v.y * sc);
    atomicAdd(o + 2, v.z * sc);
    atomicAdd(o + 3, v.w * sc);
}

// ---------------- pooling: relu + segment max ----------------
// batch[] is sorted. One wave per 128-node chunk; lane = column.
// Non-negative floats order like unsigned ints -> atomicMax(uint).
#define POOL_NODES 128
__global__ __launch_bounds__(64) void pool_kernel(
    const float* __restrict__ out2, const int* __restrict__ batch,
    unsigned int* __restrict__ g) {
    int col = threadIdx.x;
    int n0 = blockIdx.x * POOL_NODES;
    if (n0 >= N_NODES) return;
    int n1 = n0 + POOL_NODES;
    if (n1 > N_NODES) n1 = N_NODES;
    int cur = batch[n0];
    float m = 0.0f;   // relu floor
    for (int n = n0; n < n1; ++n) {
        int bnow = batch[n];
        if (bnow != cur) {
            atomicMax(&g[cur * H2 + col], __float_as_uint(m));
            cur = bnow;
            m = 0.0f;
        }
        m = fmaxf(m, out2[n * H2 + col]);
    }
    atomicMax(&g[cur * H2 + col], __float_as_uint(m));
}

// ---------------- MLP head ----------------
__global__ __launch_bounds__(256) void mlp_kernel(
    const unsigned int* __restrict__ gbits, const float* __restrict__ lin1_w,
    const float* __restrict__ lin1_b, const float* __restrict__ lin2_w,
    const float* __restrict__ lin2_b, float* __restrict__ out) {
    __shared__ float sg[G_BATCH][H2];
    __shared__ float sh[G_BATCH][H1];
    __shared__ float sw1[H2 * H1];
    for (int i = threadIdx.x; i < G_BATCH * H2; i += 256)
        sg[i / H2][i % H2] = __uint_as_float(gbits[i]);
    for (int i = threadIdx.x; i < H2 * H1; i += 256) sw1[i] = lin1_w[i];
    __syncthreads();
    for (int i = threadIdx.x; i < G_BATCH * H1; i += 256) {
        int gi = i / H1, c = i % H1;
        float a = lin1_b[c];
#pragma unroll
        for (int k = 0; k < H2; ++k) a = fmaf(sg[gi][k], sw1[k * H1 + c], a);
        sh[gi][c] = fmaxf(a, 0.0f);
    }
    __syncthreads();
    for (int i = threadIdx.x; i < G_BATCH * NC; i += 256) {
        int gi = i / NC, c = i % NC;
        float a = lin2_b[c];
#pragma unroll
        for (int k = 0; k < H1; ++k) a = fmaf(sh[gi][k], lin2_w[k * NC + c], a);
        out[gi * NC + c] = a;
    }
}

// ---------------- launch ----------------
extern "C" void kernel_launch(void* const* d_in, const int* in_sizes, int n_in,
                              void* d_out, int out_size, void* d_ws, size_t ws_size,
                              hipStream_t stream) {
    const float* x       = (const float*)d_in[0];
    const int*   eidx    = (const int*)d_in[1];
    const int*   etype   = (const int*)d_in[2];
    const int*   batch   = (const int*)d_in[3];
    const float* W1_rel  = (const float*)d_in[4];
    const float* W1_root = (const float*)d_in[5];
    const float* b1      = (const float*)d_in[6];
    const float* W2_rel  = (const float*)d_in[7];
    const float* W2_root = (const float*)d_in[8];
    const float* b2      = (const float*)d_in[9];
    const float* lin1_w  = (const float*)d_in[10];
    const float* lin1_b  = (const float*)d_in[11];
    const float* lin2_w  = (const float*)d_in[12];
    const float* lin2_b  = (const float*)d_in[13];
    const int* srcp = eidx;
    const int* dstp = eidx + N_EDGES;

    char* ws = (char*)d_ws;
    size_t off = 0;
    int*      cnt   = (int*)(ws + off);      off += (size_t)R_REL * N_NODES * 4;
    float*    inv   = (float*)(ws + off);    off += (size_t)R_REL * N_NODES * 4;
    unsigned* g     = (unsigned*)(ws + off); off += (size_t)G_BATCH * H2 * 4;
    float*    out1  = (float*)(ws + off);    off += (size_t)N_NODES * H1 * 4;
    float*    out2  = (float*)(ws + off);    off += (size_t)N_NODES * H2 * 4;
    float*    h_all = (float*)(ws + off);    off += (size_t)R_REL * N_NODES * H2 * 4;
    // total ~72 MB

    hipMemsetAsync(cnt, 0, (size_t)R_REL * N_NODES * 4, stream);
    hipMemsetAsync(g, 0, (size_t)G_BATCH * H2 * 4, stream);

    count_kernel<<<(N_EDGES + 255) / 256, 256, 0, stream>>>(etype, dstp, cnt);
    invcnt_kernel<<<(R_REL * N_NODES + 255) / 256, 256, 0, stream>>>(cnt, inv);

    transform1_kernel<<<(N_NODES + 7) / 8, 256, 0, stream>>>(
        x, W1_rel, W1_root, b1, out1, h_all);
    scatter1_kernel<<<(N_EDGES * 8 + 255) / 256, 256, 0, stream>>>(
        srcp, dstp, etype, inv, h_all, out1);

    transform2_kernel<<<(N_NODES + 3) / 4, 256, 0, stream>>>(
        out1, W2_rel, W2_root, b2, out2, h_all);
    scatter2_kernel<<<(N_EDGES * 16 + 255) / 256, 256, 0, stream>>>(
        srcp, dstp, etype, inv, h_all, out2);

    pool_kernel<<<(N_NODES + POOL_NODES - 1) / POOL_NODES, 64, 0, stream>>>(
        out2, batch, g);
    mlp_kernel<<<1, 256, 0, stream>>>(g, lin1_w, lin1_b, lin2_w, lin2_b,
                                      (float*)d_out);
}

// Round 3
// 681.837 us; speedup vs baseline: 3.3608x; 3.3608x over previous
//
#include <hip/hip_runtime.h>

#define N_NODES 50000
#define N_EDGES 1600000
#define R_REL 4
#define F_IN 32
#define H1 32
#define H2 64
#define NC 3
#define G_BATCH 64
#define NBLK ((N_NODES + 255) / 256)   // 196

// ---------------- 1. per-(relation,dst) counts ----------------
__global__ __launch_bounds__(256) void count_kernel(const int* __restrict__ etype,
                                                    const int* __restrict__ dstp,
                                                    int* __restrict__ cnt) {
    int e = blockIdx.x * 256 + threadIdx.x;
    if (e < N_EDGES) {
        atomicAdd(&cnt[etype[e] * N_NODES + dstp[e]], 1);
    }
}

// ---------------- 2. degree + inv + per-block sums ----------------
__global__ __launch_bounds__(256) void scanA_kernel(const int* __restrict__ cnt,
                                                    int* __restrict__ deg,
                                                    int* __restrict__ partial,
                                                    float* __restrict__ inv) {
    __shared__ int s[256];
    int n = blockIdx.x * 256 + threadIdx.x;
    int d = 0;
    if (n < N_NODES) {
#pragma unroll
        for (int r = 0; r < R_REL; ++r) {
            int cr = cnt[r * N_NODES + n];
            d += cr;
            inv[r * N_NODES + n] = 1.0f / (float)(cr > 1 ? cr : 1);
        }
        deg[n] = d;
    }
    s[threadIdx.x] = d;
    __syncthreads();
    for (int w = 128; w > 0; w >>= 1) {
        if (threadIdx.x < w) s[threadIdx.x] += s[threadIdx.x + w];
        __syncthreads();
    }
    if (threadIdx.x == 0) partial[blockIdx.x] = s[0];
}

// ---------------- 3. scan of block sums (exclusive), one block ----------------
__global__ __launch_bounds__(256) void scanB_kernel(int* __restrict__ partial) {
    __shared__ int s[256];
    int v = (threadIdx.x < NBLK) ? partial[threadIdx.x] : 0;
    s[threadIdx.x] = v;
    __syncthreads();
    for (int w = 1; w < 256; w <<= 1) {
        int t = (threadIdx.x >= w) ? s[threadIdx.x - w] : 0;
        __syncthreads();
        s[threadIdx.x] += t;
        __syncthreads();
    }
    if (threadIdx.x < NBLK) partial[threadIdx.x] = s[threadIdx.x] - v;  // exclusive
}

// ---------------- 4. per-node exclusive offsets + cursor init ----------------
__global__ __launch_bounds__(256) void scanC_kernel(const int* __restrict__ deg,
                                                    const int* __restrict__ partial,
                                                    int* __restrict__ off,
                                                    int* __restrict__ cursor) {
    __shared__ int s[256];
    int n = blockIdx.x * 256 + threadIdx.x;
    int d = (n < N_NODES) ? deg[n] : 0;
    s[threadIdx.x] = d;
    __syncthreads();
    for (int w = 1; w < 256; w <<= 1) {
        int t = (threadIdx.x >= w) ? s[threadIdx.x - w] : 0;
        __syncthreads();
        s[threadIdx.x] += t;
        __syncthreads();
    }
    if (n < N_NODES) {
        int o = partial[blockIdx.x] + s[threadIdx.x] - d;
        off[n] = o;
        cursor[n] = o;
    }
}

// ---------------- 5. fill edge lists (src | type<<16; N < 2^16) ----------------
__global__ __launch_bounds__(256) void fill_kernel(const int* __restrict__ srcp,
                                                   const int* __restrict__ dstp,
                                                   const int* __restrict__ etype,
                                                   int* __restrict__ cursor,
                                                   int* __restrict__ elist) {
    int e = blockIdx.x * 256 + threadIdx.x;
    if (e < N_EDGES) {
        int pos = atomicAdd(&cursor[dstp[e]], 1);
        elist[pos] = srcp[e] | (etype[e] << 16);
    }
}

// ---------------- 6. layer 1: gather-aggregate + transform, fused ReLU ----------------
// 8 nodes/block, 32 lanes/node (lane = feature column).
__global__ __launch_bounds__(256) void layer1_kernel(
    const float* __restrict__ x, const int* __restrict__ off,
    const int* __restrict__ deg, const int* __restrict__ elist,
    const float* __restrict__ inv, const float* __restrict__ W_rel,
    const float* __restrict__ W_root, const float* __restrict__ b,
    float* __restrict__ h1) {
    __shared__ float sW[5 * F_IN * H1];           // rel 0..3, root at k=4
    __shared__ float sb[H1];
    __shared__ float sxr[8][F_IN];
    __shared__ float sagg[8][R_REL][F_IN];
    for (int i = threadIdx.x; i < 4 * F_IN * H1; i += 256) sW[i] = W_rel[i];
    for (int i = threadIdx.x; i < F_IN * H1; i += 256) sW[4 * F_IN * H1 + i] = W_root[i];
    if (threadIdx.x < H1) sb[threadIdx.x] = b[threadIdx.x];

    int ln = threadIdx.x >> 5, c = threadIdx.x & 31;
    int n = blockIdx.x * 8 + ln;
    if (n < N_NODES) {
        sxr[ln][c] = x[n * F_IN + c];
        float a0 = 0.f, a1 = 0.f, a2 = 0.f, a3 = 0.f;
        int e0 = off[n], e1 = e0 + deg[n];
        for (int e = e0; e < e1; ++e) {
            int p = elist[e];
            float v = x[(p & 0xFFFF) * F_IN + c];
            int r = p >> 16;
            a0 += (r == 0) ? v : 0.0f;
            a1 += (r == 1) ? v : 0.0f;
            a2 += (r == 2) ? v : 0.0f;
            a3 += (r == 3) ? v : 0.0f;
        }
        sagg[ln][0][c] = a0 * inv[0 * N_NODES + n];
        sagg[ln][1][c] = a1 * inv[1 * N_NODES + n];
        sagg[ln][2][c] = a2 * inv[2 * N_NODES + n];
        sagg[ln][3][c] = a3 * inv[3 * N_NODES + n];
    }
    __syncthreads();
    if (n >= N_NODES) return;
    float o = sb[c];
#pragma unroll
    for (int i = 0; i < F_IN; ++i)
        o = fmaf(sxr[ln][i], sW[4 * F_IN * H1 + i * H1 + c], o);
#pragma unroll
    for (int r = 0; r < R_REL; ++r)
#pragma unroll
        for (int i = 0; i < F_IN; ++i)
            o = fmaf(sagg[ln][r][i], sW[r * F_IN * H1 + i * H1 + c], o);
    h1[n * H1 + c] = fmaxf(o, 0.0f);   // fused ReLU -> layer-2 input
}

// ---------------- 7. layer 2: same, F_out=64 (each lane does 2 out cols) ----------------
__global__ __launch_bounds__(256) void layer2_kernel(
    const float* __restrict__ h1, const int* __restrict__ off,
    const int* __restrict__ deg, const int* __restrict__ elist,
    const float* __restrict__ inv, const float* __restrict__ W_rel,
    const float* __restrict__ W_root, const float* __restrict__ b,
    float* __restrict__ out2) {
    __shared__ float sW[5 * H1 * H2];             // 40 KiB
    __shared__ float sb[H2];
    __shared__ float sxr[8][H1];
    __shared__ float sagg[8][R_REL][H1];
    for (int i = threadIdx.x; i < 4 * H1 * H2; i += 256) sW[i] = W_rel[i];
    for (int i = threadIdx.x; i < H1 * H2; i += 256) sW[4 * H1 * H2 + i] = W_root[i];
    if (threadIdx.x < H2) sb[threadIdx.x] = b[threadIdx.x];

    int ln = threadIdx.x >> 5, c = threadIdx.x & 31;
    int n = blockIdx.x * 8 + ln;
    if (n < N_NODES) {
        sxr[ln][c] = h1[n * H1 + c];
        float a0 = 0.f, a1 = 0.f, a2 = 0.f, a3 = 0.f;
        int e0 = off[n], e1 = e0 + deg[n];
        for (int e = e0; e < e1; ++e) {
            int p = elist[e];
            float v = h1[(p & 0xFFFF) * H1 + c];
            int r = p >> 16;
            a0 += (r == 0) ? v : 0.0f;
            a1 += (r == 1) ? v : 0.0f;
            a2 += (r == 2) ? v : 0.0f;
            a3 += (r == 3) ? v : 0.0f;
        }
        sagg[ln][0][c] = a0 * inv[0 * N_NODES + n];
        sagg[ln][1][c] = a1 * inv[1 * N_NODES + n];
        sagg[ln][2][c] = a2 * inv[2 * N_NODES + n];
        sagg[ln][3][c] = a3 * inv[3 * N_NODES + n];
    }
    __syncthreads();
    if (n >= N_NODES) return;
    float o0 = sb[c], o1 = sb[c + 32];
#pragma unroll
    for (int i = 0; i < H1; ++i) {
        float xv = sxr[ln][i];
        o0 = fmaf(xv, sW[4 * H1 * H2 + i * H2 + c], o0);
        o1 = fmaf(xv, sW[4 * H1 * H2 + i * H2 + c + 32], o1);
    }
#pragma unroll
    for (int r = 0; r < R_REL; ++r)
#pragma unroll
        for (int i = 0; i < H1; ++i) {
            float av = sagg[ln][r][i];
            o0 = fmaf(av, sW[r * H1 * H2 + i * H2 + c], o0);
            o1 = fmaf(av, sW[r * H1 * H2 + i * H2 + c + 32], o1);
        }
    out2[n * H2 + c] = o0;            // raw (pool applies relu via max with 0)
    out2[n * H2 + c + 32] = o1;
}

// ---------------- 8. pooling: relu + segment max ----------------
#define POOL_NODES 128
__global__ __launch_bounds__(64) void pool_kernel(
    const float* __restrict__ out2, const int* __restrict__ batch,
    unsigned int* __restrict__ g) {
    int col = threadIdx.x;
    int n0 = blockIdx.x * POOL_NODES;
    if (n0 >= N_NODES) return;
    int n1 = n0 + POOL_NODES;
    if (n1 > N_NODES) n1 = N_NODES;
    int cur = batch[n0];
    float m = 0.0f;   // relu floor; also empty-graph guard value
    for (int n = n0; n < n1; ++n) {
        int bnow = batch[n];
        if (bnow != cur) {
            atomicMax(&g[cur * H2 + col], __float_as_uint(m));
            cur = bnow;
            m = 0.0f;
        }
        m = fmaxf(m, out2[n * H2 + col]);
    }
    atomicMax(&g[cur * H2 + col], __float_as_uint(m));
}

// ---------------- 9. MLP head ----------------
__global__ __launch_bounds__(256) void mlp_kernel(
    const unsigned int* __restrict__ gbits, const float* __restrict__ lin1_w,
    const float* __restrict__ lin1_b, const float* __restrict__ lin2_w,
    const float* __restrict__ lin2_b, float* __restrict__ out) {
    __shared__ float sg[G_BATCH][H2];
    __shared__ float sh[G_BATCH][H1];
    __shared__ float sw1[H2 * H1];
    for (int i = threadIdx.x; i < G_BATCH * H2; i += 256)
        sg[i / H2][i % H2] = __uint_as_float(gbits[i]);
    for (int i = threadIdx.x; i < H2 * H1; i += 256) sw1[i] = lin1_w[i];
    __syncthreads();
    for (int i = threadIdx.x; i < G_BATCH * H1; i += 256) {
        int gi = i / H1, c = i % H1;
        float a = lin1_b[c];
#pragma unroll
        for (int k = 0; k < H2; ++k) a = fmaf(sg[gi][k], sw1[k * H1 + c], a);
        sh[gi][c] = fmaxf(a, 0.0f);
    }
    __syncthreads();
    for (int i = threadIdx.x; i < G_BATCH * NC; i += 256) {
        int gi = i / NC, c = i % NC;
        float a = lin2_b[c];
#pragma unroll
        for (int k = 0; k < H1; ++k) a = fmaf(sh[gi][k], lin2_w[k * NC + c], a);
        out[gi * NC + c] = a;
    }
}

// ---------------- launch ----------------
extern "C" void kernel_launch(void* const* d_in, const int* in_sizes, int n_in,
                              void* d_out, int out_size, void* d_ws, size_t ws_size,
                              hipStream_t stream) {
    const float* x       = (const float*)d_in[0];
    const int*   eidx    = (const int*)d_in[1];
    const int*   etype   = (const int*)d_in[2];
    const int*   batch   = (const int*)d_in[3];
    const float* W1_rel  = (const float*)d_in[4];
    const float* W1_root = (const float*)d_in[5];
    const float* b1      = (const float*)d_in[6];
    const float* W2_rel  = (const float*)d_in[7];
    const float* W2_root = (const float*)d_in[8];
    const float* b2      = (const float*)d_in[9];
    const float* lin1_w  = (const float*)d_in[10];
    const float* lin1_b  = (const float*)d_in[11];
    const float* lin2_w  = (const float*)d_in[12];
    const float* lin2_b  = (const float*)d_in[13];
    const int* srcp = eidx;
    const int* dstp = eidx + N_EDGES;

    char* ws = (char*)d_ws;
    size_t o = 0;
    int*      cnt     = (int*)(ws + o);      o += (size_t)R_REL * N_NODES * 4;
    float*    inv     = (float*)(ws + o);    o += (size_t)R_REL * N_NODES * 4;
    int*      degv    = (int*)(ws + o);      o += (size_t)N_NODES * 4;
    int*      offv    = (int*)(ws + o);      o += (size_t)N_NODES * 4;
    int*      cursor  = (int*)(ws + o);      o += (size_t)N_NODES * 4;
    int*      partial = (int*)(ws + o);      o += (size_t)256 * 4;
    int*      elist   = (int*)(ws + o);      o += (size_t)N_EDGES * 4;
    unsigned* g       = (unsigned*)(ws + o); o += (size_t)G_BATCH * H2 * 4;
    float*    h1      = (float*)(ws + o);    o += (size_t)N_NODES * H1 * 4;
    float*    out2    = (float*)(ws + o);    o += (size_t)N_NODES * H2 * 4;
    // total ~29 MB

    hipMemsetAsync(cnt, 0, (size_t)R_REL * N_NODES * 4, stream);
    hipMemsetAsync(g, 0, (size_t)G_BATCH * H2 * 4, stream);

    count_kernel<<<(N_EDGES + 255) / 256, 256, 0, stream>>>(etype, dstp, cnt);
    scanA_kernel<<<NBLK, 256, 0, stream>>>(cnt, degv, partial, inv);
    scanB_kernel<<<1, 256, 0, stream>>>(partial);
    scanC_kernel<<<NBLK, 256, 0, stream>>>(degv, partial, offv, cursor);
    fill_kernel<<<(N_EDGES + 255) / 256, 256, 0, stream>>>(srcp, dstp, etype,
                                                           cursor, elist);

    layer1_kernel<<<(N_NODES + 7) / 8, 256, 0, stream>>>(
        x, offv, degv, elist, inv, W1_rel, W1_root, b1, h1);
    layer2_kernel<<<(N_NODES + 7) / 8, 256, 0, stream>>>(
        h1, offv, degv, elist, inv, W2_rel, W2_root, b2, out2);

    pool_kernel<<<(N_NODES + POOL_NODES - 1) / POOL_NODES, 64, 0, stream>>>(
        out2, batch, g);
    mlp_kernel<<<1, 256, 0, stream>>>(g, lin1_w, lin1_b, lin2_w, lin2_b,
                                      (float*)d_out);
}

// Round 4
// 489.682 us; speedup vs baseline: 4.6796x; 1.3924x over previous
//
#include <hip/hip_runtime.h>

#define N_NODES 50000
#define N_EDGES 1600000
#define R_REL 4
#define F_IN 32
#define H1 32
#define H2 64
#define NC 3
#define G_BATCH 64
#define NBLK ((N_NODES + 255) / 256)   // 196
#define SENTINEL (R_REL << 16)         // r=4 (never matches), src=0 (safe read)

// ---------------- 1. per-(relation,dst) counts ----------------
__global__ __launch_bounds__(256) void count_kernel(const int* __restrict__ etype,
                                                    const int* __restrict__ dstp,
                                                    int* __restrict__ cnt) {
    int e = blockIdx.x * 256 + threadIdx.x;
    if (e < N_EDGES) {
        atomicAdd(&cnt[etype[e] * N_NODES + dstp[e]], 1);
    }
}

// ---------------- 2. degree + inv + per-block sums ----------------
__global__ __launch_bounds__(256) void scanA_kernel(const int* __restrict__ cnt,
                                                    int* __restrict__ deg,
                                                    int* __restrict__ partial,
                                                    float* __restrict__ inv) {
    __shared__ int s[256];
    int n = blockIdx.x * 256 + threadIdx.x;
    int d = 0;
    if (n < N_NODES) {
#pragma unroll
        for (int r = 0; r < R_REL; ++r) {
            int cr = cnt[r * N_NODES + n];
            d += cr;
            inv[r * N_NODES + n] = 1.0f / (float)(cr > 1 ? cr : 1);
        }
        deg[n] = d;
    }
    s[threadIdx.x] = d;
    __syncthreads();
    for (int w = 128; w > 0; w >>= 1) {
        if (threadIdx.x < w) s[threadIdx.x] += s[threadIdx.x + w];
        __syncthreads();
    }
    if (threadIdx.x == 0) partial[blockIdx.x] = s[0];
}

// ---------------- 3. scan of block sums (exclusive), one block ----------------
__global__ __launch_bounds__(256) void scanB_kernel(int* __restrict__ partial) {
    __shared__ int s[256];
    int v = (threadIdx.x < NBLK) ? partial[threadIdx.x] : 0;
    s[threadIdx.x] = v;
    __syncthreads();
    for (int w = 1; w < 256; w <<= 1) {
        int t = (threadIdx.x >= w) ? s[threadIdx.x - w] : 0;
        __syncthreads();
        s[threadIdx.x] += t;
        __syncthreads();
    }
    if (threadIdx.x < NBLK) partial[threadIdx.x] = s[threadIdx.x] - v;  // exclusive
}

// ---------------- 4. per-node exclusive offsets + cursor init ----------------
__global__ __launch_bounds__(256) void scanC_kernel(const int* __restrict__ deg,
                                                    const int* __restrict__ partial,
                                                    int* __restrict__ off,
                                                    int* __restrict__ cursor) {
    __shared__ int s[256];
    int n = blockIdx.x * 256 + threadIdx.x;
    int d = (n < N_NODES) ? deg[n] : 0;
    s[threadIdx.x] = d;
    __syncthreads();
    for (int w = 1; w < 256; w <<= 1) {
        int t = (threadIdx.x >= w) ? s[threadIdx.x - w] : 0;
        __syncthreads();
        s[threadIdx.x] += t;
        __syncthreads();
    }
    if (n < N_NODES) {
        int o = partial[blockIdx.x] + s[threadIdx.x] - d;
        off[n] = o;
        cursor[n] = o;
    }
}

// ---------------- 5. fill edge lists (src | type<<16; N < 2^16) ----------------
__global__ __launch_bounds__(256) void fill_kernel(const int* __restrict__ srcp,
                                                   const int* __restrict__ dstp,
                                                   const int* __restrict__ etype,
                                                   int* __restrict__ cursor,
                                                   int* __restrict__ elist) {
    int e = blockIdx.x * 256 + threadIdx.x;
    if (e < N_EDGES) {
        int pos = atomicAdd(&cursor[dstp[e]], 1);
        elist[pos] = srcp[e] | (etype[e] << 16);
    }
}

// ---------------- 6. layer 1: gather-aggregate + transform, fused ReLU -------
// 8 nodes/block, 32 lanes/node (lane = feature column). No __syncthreads:
// each 32-lane group only touches its own LDS rows (intra-wave dependence).
// Edge loop: 32 coalesced elist loads -> shfl broadcast -> batched gathers.
__global__ __launch_bounds__(256, 6) void layer1_kernel(
    const float* __restrict__ x, const int* __restrict__ off,
    const int* __restrict__ deg, const int* __restrict__ elist,
    const float* __restrict__ inv, const float* __restrict__ W_rel,
    const float* __restrict__ W_root, const float* __restrict__ b,
    float* __restrict__ h1) {
    __shared__ float sxr[8][F_IN];
    __shared__ float sagg[8][R_REL][F_IN];

    int ln = threadIdx.x >> 5, c = threadIdx.x & 31;
    int n = blockIdx.x * 8 + ln;
    if (n >= N_NODES) return;

    sxr[ln][c] = x[n * F_IN + c];
    float a0 = 0.f, a1 = 0.f, a2 = 0.f, a3 = 0.f;
    int e0 = off[n], e1 = e0 + deg[n];
    for (int eb = e0; eb < e1; eb += 32) {
        int idx = eb + c;
        int pv = (idx < e1) ? elist[idx] : SENTINEL;
#pragma unroll
        for (int j0 = 0; j0 < 32; j0 += 8) {
#pragma unroll
            for (int j = j0; j < j0 + 8; ++j) {
                int p = __shfl(pv, j, 32);
                float v = x[(p & 0xFFFF) * F_IN + c];
                int r = p >> 16;
                a0 += (r == 0) ? v : 0.0f;
                a1 += (r == 1) ? v : 0.0f;
                a2 += (r == 2) ? v : 0.0f;
                a3 += (r == 3) ? v : 0.0f;
            }
        }
    }
    sagg[ln][0][c] = a0 * inv[0 * N_NODES + n];
    sagg[ln][1][c] = a1 * inv[1 * N_NODES + n];
    sagg[ln][2][c] = a2 * inv[2 * N_NODES + n];
    sagg[ln][3][c] = a3 * inv[3 * N_NODES + n];

    // epilogue: weights straight from global (L1/L2-resident broadcast)
    float o = b[c];
#pragma unroll
    for (int i = 0; i < F_IN; ++i)
        o = fmaf(sxr[ln][i], W_root[i * H1 + c], o);
#pragma unroll
    for (int r = 0; r < R_REL; ++r)
#pragma unroll
        for (int i = 0; i < F_IN; ++i)
            o = fmaf(sagg[ln][r][i], W_rel[r * F_IN * H1 + i * H1 + c], o);
    h1[n * H1 + c] = fmaxf(o, 0.0f);   // fused ReLU -> layer-2 input
}

// ---------------- 7. layer 2: same, F_out=64 (each lane does 2 out cols) -----
__global__ __launch_bounds__(256, 6) void layer2_kernel(
    const float* __restrict__ h1, const int* __restrict__ off,
    const int* __restrict__ deg, const int* __restrict__ elist,
    const float* __restrict__ inv, const float* __restrict__ W_rel,
    const float* __restrict__ W_root, const float* __restrict__ b,
    float* __restrict__ out2) {
    __shared__ float sxr[8][H1];
    __shared__ float sagg[8][R_REL][H1];

    int ln = threadIdx.x >> 5, c = threadIdx.x & 31;
    int n = blockIdx.x * 8 + ln;
    if (n >= N_NODES) return;

    sxr[ln][c] = h1[n * H1 + c];
    float a0 = 0.f, a1 = 0.f, a2 = 0.f, a3 = 0.f;
    int e0 = off[n], e1 = e0 + deg[n];
    for (int eb = e0; eb < e1; eb += 32) {
        int idx = eb + c;
        int pv = (idx < e1) ? elist[idx] : SENTINEL;
#pragma unroll
        for (int j0 = 0; j0 < 32; j0 += 8) {
#pragma unroll
            for (int j = j0; j < j0 + 8; ++j) {
                int p = __shfl(pv, j, 32);
                float v = h1[(p & 0xFFFF) * H1 + c];
                int r = p >> 16;
                a0 += (r == 0) ? v : 0.0f;
                a1 += (r == 1) ? v : 0.0f;
                a2 += (r == 2) ? v : 0.0f;
                a3 += (r == 3) ? v : 0.0f;
            }
        }
    }
    sagg[ln][0][c] = a0 * inv[0 * N_NODES + n];
    sagg[ln][1][c] = a1 * inv[1 * N_NODES + n];
    sagg[ln][2][c] = a2 * inv[2 * N_NODES + n];
    sagg[ln][3][c] = a3 * inv[3 * N_NODES + n];

    float o0 = b[c], o1 = b[c + 32];
#pragma unroll
    for (int i = 0; i < H1; ++i) {
        float xv = sxr[ln][i];
        o0 = fmaf(xv, W_root[i * H2 + c], o0);
        o1 = fmaf(xv, W_root[i * H2 + c + 32], o1);
    }
#pragma unroll
    for (int r = 0; r < R_REL; ++r)
#pragma unroll
        for (int i = 0; i < H1; ++i) {
            float av = sagg[ln][r][i];
            o0 = fmaf(av, W_rel[r * H1 * H2 + i * H2 + c], o0);
            o1 = fmaf(av, W_rel[r * H1 * H2 + i * H2 + c + 32], o1);
        }
    out2[n * H2 + c] = o0;            // raw (pool applies relu via max with 0)
    out2[n * H2 + c + 32] = o1;
}

// ---------------- 8. pooling: relu + segment max ----------------
#define POOL_NODES 32
__global__ __launch_bounds__(64) void pool_kernel(
    const float* __restrict__ out2, const int* __restrict__ batch,
    unsigned int* __restrict__ g) {
    int col = threadIdx.x;
    int n0 = blockIdx.x * POOL_NODES;
    if (n0 >= N_NODES) return;
    int n1 = n0 + POOL_NODES;
    if (n1 > N_NODES) n1 = N_NODES;
    int cur = batch[n0];
    float m = 0.0f;   // relu floor; also empty-graph guard value
    for (int n = n0; n < n1; ++n) {
        int bnow = batch[n];
        if (bnow != cur) {
            atomicMax(&g[cur * H2 + col], __float_as_uint(m));
            cur = bnow;
            m = 0.0f;
        }
        m = fmaxf(m, out2[n * H2 + col]);
    }
    atomicMax(&g[cur * H2 + col], __float_as_uint(m));
}

// ---------------- 9. MLP head ----------------
__global__ __launch_bounds__(256) void mlp_kernel(
    const unsigned int* __restrict__ gbits, const float* __restrict__ lin1_w,
    const float* __restrict__ lin1_b, const float* __restrict__ lin2_w,
    const float* __restrict__ lin2_b, float* __restrict__ out) {
    __shared__ float sg[G_BATCH][H2];
    __shared__ float sh[G_BATCH][H1];
    __shared__ float sw1[H2 * H1];
    for (int i = threadIdx.x; i < G_BATCH * H2; i += 256)
        sg[i / H2][i % H2] = __uint_as_float(gbits[i]);
    for (int i = threadIdx.x; i < H2 * H1; i += 256) sw1[i] = lin1_w[i];
    __syncthreads();
    for (int i = threadIdx.x; i < G_BATCH * H1; i += 256) {
        int gi = i / H1, c = i % H1;
        float a = lin1_b[c];
#pragma unroll
        for (int k = 0; k < H2; ++k) a = fmaf(sg[gi][k], sw1[k * H1 + c], a);
        sh[gi][c] = fmaxf(a, 0.0f);
    }
    __syncthreads();
    for (int i = threadIdx.x; i < G_BATCH * NC; i += 256) {
        int gi = i / NC, c = i % NC;
        float a = lin2_b[c];
#pragma unroll
        for (int k = 0; k < H1; ++k) a = fmaf(sh[gi][k], lin2_w[k * NC + c], a);
        out[gi * NC + c] = a;
    }
}

// ---------------- launch ----------------
extern "C" void kernel_launch(void* const* d_in, const int* in_sizes, int n_in,
                              void* d_out, int out_size, void* d_ws, size_t ws_size,
                              hipStream_t stream) {
    const float* x       = (const float*)d_in[0];
    const int*   eidx    = (const int*)d_in[1];
    const int*   etype   = (const int*)d_in[2];
    const int*   batch   = (const int*)d_in[3];
    const float* W1_rel  = (const float*)d_in[4];
    const float* W1_root = (const float*)d_in[5];
    const float* b1      = (const float*)d_in[6];
    const float* W2_rel  = (const float*)d_in[7];
    const float* W2_root = (const float*)d_in[8];
    const float* b2      = (const float*)d_in[9];
    const float* lin1_w  = (const float*)d_in[10];
    const float* lin1_b  = (const float*)d_in[11];
    const float* lin2_w  = (const float*)d_in[12];
    const float* lin2_b  = (const float*)d_in[13];
    const int* srcp = eidx;
    const int* dstp = eidx + N_EDGES;

    char* ws = (char*)d_ws;
    size_t o = 0;
    int*      cnt     = (int*)(ws + o);      o += (size_t)R_REL * N_NODES * 4;
    float*    inv     = (float*)(ws + o);    o += (size_t)R_REL * N_NODES * 4;
    int*      degv    = (int*)(ws + o);      o += (size_t)N_NODES * 4;
    int*      offv    = (int*)(ws + o);      o += (size_t)N_NODES * 4;
    int*      cursor  = (int*)(ws + o);      o += (size_t)N_NODES * 4;
    int*      partial = (int*)(ws + o);      o += (size_t)256 * 4;
    int*      elist   = (int*)(ws + o);      o += (size_t)N_EDGES * 4;
    unsigned* g       = (unsigned*)(ws + o); o += (size_t)G_BATCH * H2 * 4;
    float*    h1      = (float*)(ws + o);    o += (size_t)N_NODES * H1 * 4;
    float*    out2    = (float*)(ws + o);    o += (size_t)N_NODES * H2 * 4;
    // total ~29 MB

    hipMemsetAsync(cnt, 0, (size_t)R_REL * N_NODES * 4, stream);
    hipMemsetAsync(g, 0, (size_t)G_BATCH * H2 * 4, stream);

    count_kernel<<<(N_EDGES + 255) / 256, 256, 0, stream>>>(etype, dstp, cnt);
    scanA_kernel<<<NBLK, 256, 0, stream>>>(cnt, degv, partial, inv);
    scanB_kernel<<<1, 256, 0, stream>>>(partial);
    scanC_kernel<<<NBLK, 256, 0, stream>>>(degv, partial, offv, cursor);
    fill_kernel<<<(N_EDGES + 255) / 256, 256, 0, stream>>>(srcp, dstp, etype,
                                                           cursor, elist);

    layer1_kernel<<<(N_NODES + 7) / 8, 256, 0, stream>>>(
        x, offv, degv, elist, inv, W1_rel, W1_root, b1, h1);
    layer2_kernel<<<(N_NODES + 7) / 8, 256, 0, stream>>>(
        h1, offv, degv, elist, inv, W2_rel, W2_root, b2, out2);

    pool_kernel<<<(N_NODES + POOL_NODES - 1) / POOL_NODES, 64, 0, stream>>>(
        out2, batch, g);
    mlp_kernel<<<1, 256, 0, stream>>>(g, lin1_w, lin1_b, lin2_w, lin2_b,
                                      (float*)d_out);
}

// Round 5
// 358.760 us; speedup vs baseline: 6.3873x; 1.3649x over previous
//
#include <hip/hip_runtime.h>

#define N_NODES 50000
#define N_EDGES 1600000
#define R_REL 4
#define F_IN 32
#define H1 32
#define H2 64
#define NC 3
#define G_BATCH 64
#define BKT 196                        // buckets = ceil(N/256); also scan blocks
#define CHUNK 6400                     // edges per binning block (1.6M/6400=250)
#define NBIN (N_EDGES / CHUNK)         // 250 exactly
#define SENTINEL (R_REL << 16)         // r=4 (never matches), src=0 (safe read)

// ---------------- 1. coarse bucket histogram (bucket = dst>>8) ----------------
__global__ __launch_bounds__(256) void bcount_kernel(const int* __restrict__ dstp,
                                                     int* __restrict__ bucketCnt) {
    __shared__ int h[BKT];
    for (int i = threadIdx.x; i < BKT; i += 256) h[i] = 0;
    __syncthreads();
    int e0 = blockIdx.x * CHUNK;
    for (int e = e0 + threadIdx.x; e < e0 + CHUNK; e += 256)
        atomicAdd(&h[dstp[e] >> 8], 1);
    __syncthreads();
    for (int i = threadIdx.x; i < BKT; i += 256)
        if (h[i]) atomicAdd(&bucketCnt[i], h[i]);
}

// ---------------- 2. exclusive scan of bucket counts ----------------
__global__ __launch_bounds__(256) void bscan_kernel(const int* __restrict__ bucketCnt,
                                                    int* __restrict__ bucketOff,
                                                    int* __restrict__ bucketCursor) {
    __shared__ int s[256];
    int v = (threadIdx.x < BKT) ? bucketCnt[threadIdx.x] : 0;
    s[threadIdx.x] = v;
    __syncthreads();
    for (int w = 1; w < 256; w <<= 1) {
        int t = (threadIdx.x >= w) ? s[threadIdx.x - w] : 0;
        __syncthreads();
        s[threadIdx.x] += t;
        __syncthreads();
    }
    if (threadIdx.x < BKT) {
        int o = s[threadIdx.x] - v;
        bucketOff[threadIdx.x] = o;
        bucketCursor[threadIdx.x] = o;
    }
}

// ---------------- 3. bin edges into bucket-contiguous regions ----------------
// record = src | type<<16 | dstLocal<<18  (src<2^16, type<4, dstLocal<256)
__global__ __launch_bounds__(256) void bin_kernel(const int* __restrict__ srcp,
                                                  const int* __restrict__ dstp,
                                                  const int* __restrict__ etype,
                                                  int* __restrict__ bucketCursor,
                                                  int* __restrict__ binned) {
    __shared__ int h[BKT];    // local histogram, then global base per bucket
    __shared__ int lc[BKT];   // local cursor
    for (int i = threadIdx.x; i < BKT; i += 256) { h[i] = 0; lc[i] = 0; }
    __syncthreads();
    int e0 = blockIdx.x * CHUNK;
    for (int e = e0 + threadIdx.x; e < e0 + CHUNK; e += 256)
        atomicAdd(&h[dstp[e] >> 8], 1);
    __syncthreads();
    for (int i = threadIdx.x; i < BKT; i += 256) {
        int c = h[i];
        h[i] = c ? atomicAdd(&bucketCursor[i], c) : 0;   // reserve contiguous slice
    }
    __syncthreads();
    for (int e = e0 + threadIdx.x; e < e0 + CHUNK; e += 256) {
        int d = dstp[e];
        int b = d >> 8;
        int rank = atomicAdd(&lc[b], 1);
        binned[h[b] + rank] = srcp[e] | (etype[e] << 16) | ((d & 0xFF) << 18);
    }
}

// ---------------- 4. per-(rel,node) counts + inv + deg + block sums ----------
// One block per bucket; all counting in LDS (no global atomics).
__global__ __launch_bounds__(256) void bcnt2_kernel(const int* __restrict__ binned,
                                                    const int* __restrict__ bucketOff,
                                                    const int* __restrict__ bucketCnt,
                                                    float* __restrict__ inv,
                                                    int* __restrict__ deg,
                                                    int* __restrict__ partial) {
    __shared__ int cnt4[256 * R_REL];
    __shared__ int s[256];
    for (int i = threadIdx.x; i < 256 * R_REL; i += 256) cnt4[i] = 0;
    __syncthreads();
    int b = blockIdx.x;
    int i0 = bucketOff[b], i1 = i0 + bucketCnt[b];
    for (int i = i0 + threadIdx.x; i < i1; i += 256) {
        int p = binned[i];
        atomicAdd(&cnt4[((p >> 18) & 0xFF) * R_REL + ((p >> 16) & 3)], 1);
    }
    __syncthreads();
    int n = b * 256 + threadIdx.x;
    int d = 0;
    if (n < N_NODES) {
#pragma unroll
        for (int r = 0; r < R_REL; ++r) {
            int cr = cnt4[threadIdx.x * R_REL + r];
            d += cr;
            inv[r * N_NODES + n] = 1.0f / (float)(cr > 1 ? cr : 1);
        }
        deg[n] = d;
    }
    s[threadIdx.x] = d;
    __syncthreads();
    for (int w = 128; w > 0; w >>= 1) {
        if (threadIdx.x < w) s[threadIdx.x] += s[threadIdx.x + w];
        __syncthreads();
    }
    if (threadIdx.x == 0) partial[b] = s[0];
}

// ---------------- 5. scan of block sums (exclusive), one block ----------------
__global__ __launch_bounds__(256) void scanB_kernel(int* __restrict__ partial) {
    __shared__ int s[256];
    int v = (threadIdx.x < BKT) ? partial[threadIdx.x] : 0;
    s[threadIdx.x] = v;
    __syncthreads();
    for (int w = 1; w < 256; w <<= 1) {
        int t = (threadIdx.x >= w) ? s[threadIdx.x - w] : 0;
        __syncthreads();
        s[threadIdx.x] += t;
        __syncthreads();
    }
    if (threadIdx.x < BKT) partial[threadIdx.x] = s[threadIdx.x] - v;  // exclusive
}

// ---------------- 6. per-node exclusive offsets ----------------
__global__ __launch_bounds__(256) void scanC_kernel(const int* __restrict__ deg,
                                                    const int* __restrict__ partial,
                                                    int* __restrict__ off) {
    __shared__ int s[256];
    int n = blockIdx.x * 256 + threadIdx.x;
    int d = (n < N_NODES) ? deg[n] : 0;
    s[threadIdx.x] = d;
    __syncthreads();
    for (int w = 1; w < 256; w <<= 1) {
        int t = (threadIdx.x >= w) ? s[threadIdx.x - w] : 0;
        __syncthreads();
        s[threadIdx.x] += t;
        __syncthreads();
    }
    if (n < N_NODES) off[n] = partial[blockIdx.x] + s[threadIdx.x] - d;
}

// ---------------- 7. final CSR scatter, bucket-local (dense writes) ----------
__global__ __launch_bounds__(256) void bscatter_kernel(const int* __restrict__ binned,
                                                       const int* __restrict__ bucketOff,
                                                       const int* __restrict__ bucketCnt,
                                                       const int* __restrict__ off,
                                                       int* __restrict__ elist) {
    __shared__ int cur[256];
    int b = blockIdx.x;
    int n = b * 256 + threadIdx.x;
    cur[threadIdx.x] = (n < N_NODES) ? off[n] : 0;
    __syncthreads();
    int i0 = bucketOff[b], i1 = i0 + bucketCnt[b];
    for (int i = i0 + threadIdx.x; i < i1; i += 256) {
        int p = binned[i];
        int pos = atomicAdd(&cur[(p >> 18) & 0xFF], 1);
        elist[pos] = p & 0x3FFFF;   // src | type<<16
    }
}

// ---------------- 8. layer 1: gather-aggregate + transform, fused ReLU -------
__global__ __launch_bounds__(256, 6) void layer1_kernel(
    const float* __restrict__ x, const int* __restrict__ off,
    const int* __restrict__ deg, const int* __restrict__ elist,
    const float* __restrict__ inv, const float* __restrict__ W_rel,
    const float* __restrict__ W_root, const float* __restrict__ b,
    float* __restrict__ h1) {
    __shared__ float sxr[8][F_IN];
    __shared__ float sagg[8][R_REL][F_IN];

    int ln = threadIdx.x >> 5, c = threadIdx.x & 31;
    int n = blockIdx.x * 8 + ln;
    if (n >= N_NODES) return;

    sxr[ln][c] = x[n * F_IN + c];
    float a0 = 0.f, a1 = 0.f, a2 = 0.f, a3 = 0.f;
    int e0 = off[n], e1 = e0 + deg[n];
    for (int eb = e0; eb < e1; eb += 32) {
        int idx = eb + c;
        int pv = (idx < e1) ? elist[idx] : SENTINEL;
#pragma unroll
        for (int j0 = 0; j0 < 32; j0 += 8) {
#pragma unroll
            for (int j = j0; j < j0 + 8; ++j) {
                int p = __shfl(pv, j, 32);
                float v = x[(p & 0xFFFF) * F_IN + c];
                int r = p >> 16;
                a0 += (r == 0) ? v : 0.0f;
                a1 += (r == 1) ? v : 0.0f;
                a2 += (r == 2) ? v : 0.0f;
                a3 += (r == 3) ? v : 0.0f;
            }
        }
    }
    sagg[ln][0][c] = a0 * inv[0 * N_NODES + n];
    sagg[ln][1][c] = a1 * inv[1 * N_NODES + n];
    sagg[ln][2][c] = a2 * inv[2 * N_NODES + n];
    sagg[ln][3][c] = a3 * inv[3 * N_NODES + n];

    float o = b[c];
#pragma unroll
    for (int i = 0; i < F_IN; ++i)
        o = fmaf(sxr[ln][i], W_root[i * H1 + c], o);
#pragma unroll
    for (int r = 0; r < R_REL; ++r)
#pragma unroll
        for (int i = 0; i < F_IN; ++i)
            o = fmaf(sagg[ln][r][i], W_rel[r * F_IN * H1 + i * H1 + c], o);
    h1[n * H1 + c] = fmaxf(o, 0.0f);
}

// ---------------- 9. layer 2: same, F_out=64 ----------------
__global__ __launch_bounds__(256, 6) void layer2_kernel(
    const float* __restrict__ h1, const int* __restrict__ off,
    const int* __restrict__ deg, const int* __restrict__ elist,
    const float* __restrict__ inv, const float* __restrict__ W_rel,
    const float* __restrict__ W_root, const float* __restrict__ b,
    float* __restrict__ out2) {
    __shared__ float sxr[8][H1];
    __shared__ float sagg[8][R_REL][H1];

    int ln = threadIdx.x >> 5, c = threadIdx.x & 31;
    int n = blockIdx.x * 8 + ln;
    if (n >= N_NODES) return;

    sxr[ln][c] = h1[n * H1 + c];
    float a0 = 0.f, a1 = 0.f, a2 = 0.f, a3 = 0.f;
    int e0 = off[n], e1 = e0 + deg[n];
    for (int eb = e0; eb < e1; eb += 32) {
        int idx = eb + c;
        int pv = (idx < e1) ? elist[idx] : SENTINEL;
#pragma unroll
        for (int j0 = 0; j0 < 32; j0 += 8) {
#pragma unroll
            for (int j = j0; j < j0 + 8; ++j) {
                int p = __shfl(pv, j, 32);
                float v = h1[(p & 0xFFFF) * H1 + c];
                int r = p >> 16;
                a0 += (r == 0) ? v : 0.0f;
                a1 += (r == 1) ? v : 0.0f;
                a2 += (r == 2) ? v : 0.0f;
                a3 += (r == 3) ? v : 0.0f;
            }
        }
    }
    sagg[ln][0][c] = a0 * inv[0 * N_NODES + n];
    sagg[ln][1][c] = a1 * inv[1 * N_NODES + n];
    sagg[ln][2][c] = a2 * inv[2 * N_NODES + n];
    sagg[ln][3][c] = a3 * inv[3 * N_NODES + n];

    float o0 = b[c], o1 = b[c + 32];
#pragma unroll
    for (int i = 0; i < H1; ++i) {
        float xv = sxr[ln][i];
        o0 = fmaf(xv, W_root[i * H2 + c], o0);
        o1 = fmaf(xv, W_root[i * H2 + c + 32], o1);
    }
#pragma unroll
    for (int r = 0; r < R_REL; ++r)
#pragma unroll
        for (int i = 0; i < H1; ++i) {
            float av = sagg[ln][r][i];
            o0 = fmaf(av, W_rel[r * H1 * H2 + i * H2 + c], o0);
            o1 = fmaf(av, W_rel[r * H1 * H2 + i * H2 + c + 32], o1);
        }
    out2[n * H2 + c] = o0;
    out2[n * H2 + c + 32] = o1;
}

// ---------------- 10. pooling: relu + segment max ----------------
#define POOL_NODES 32
__global__ __launch_bounds__(64) void pool_kernel(
    const float* __restrict__ out2, const int* __restrict__ batch,
    unsigned int* __restrict__ g) {
    int col = threadIdx.x;
    int n0 = blockIdx.x * POOL_NODES;
    if (n0 >= N_NODES) return;
    int n1 = n0 + POOL_NODES;
    if (n1 > N_NODES) n1 = N_NODES;
    int cur = batch[n0];
    float m = 0.0f;
    for (int n = n0; n < n1; ++n) {
        int bnow = batch[n];
        if (bnow != cur) {
            atomicMax(&g[cur * H2 + col], __float_as_uint(m));
            cur = bnow;
            m = 0.0f;
        }
        m = fmaxf(m, out2[n * H2 + col]);
    }
    atomicMax(&g[cur * H2 + col], __float_as_uint(m));
}

// ---------------- 11. MLP head ----------------
__global__ __launch_bounds__(256) void mlp_kernel(
    const unsigned int* __restrict__ gbits, const float* __restrict__ lin1_w,
    const float* __restrict__ lin1_b, const float* __restrict__ lin2_w,
    const float* __restrict__ lin2_b, float* __restrict__ out) {
    __shared__ float sg[G_BATCH][H2];
    __shared__ float sh[G_BATCH][H1];
    __shared__ float sw1[H2 * H1];
    for (int i = threadIdx.x; i < G_BATCH * H2; i += 256)
        sg[i / H2][i % H2] = __uint_as_float(gbits[i]);
    for (int i = threadIdx.x; i < H2 * H1; i += 256) sw1[i] = lin1_w[i];
    __syncthreads();
    for (int i = threadIdx.x; i < G_BATCH * H1; i += 256) {
        int gi = i / H1, c = i % H1;
        float a = lin1_b[c];
#pragma unroll
        for (int k = 0; k < H2; ++k) a = fmaf(sg[gi][k], sw1[k * H1 + c], a);
        sh[gi][c] = fmaxf(a, 0.0f);
    }
    __syncthreads();
    for (int i = threadIdx.x; i < G_BATCH * NC; i += 256) {
        int gi = i / NC, c = i % NC;
        float a = lin2_b[c];
#pragma unroll
        for (int k = 0; k < H1; ++k) a = fmaf(sh[gi][k], lin2_w[k * NC + c], a);
        out[gi * NC + c] = a;
    }
}

// ---------------- launch ----------------
extern "C" void kernel_launch(void* const* d_in, const int* in_sizes, int n_in,
                              void* d_out, int out_size, void* d_ws, size_t ws_size,
                              hipStream_t stream) {
    const float* x       = (const float*)d_in[0];
    const int*   eidx    = (const int*)d_in[1];
    const int*   etype   = (const int*)d_in[2];
    const int*   batch   = (const int*)d_in[3];
    const float* W1_rel  = (const float*)d_in[4];
    const float* W1_root = (const float*)d_in[5];
    const float* b1      = (const float*)d_in[6];
    const float* W2_rel  = (const float*)d_in[7];
    const float* W2_root = (const float*)d_in[8];
    const float* b2      = (const float*)d_in[9];
    const float* lin1_w  = (const float*)d_in[10];
    const float* lin1_b  = (const float*)d_in[11];
    const float* lin2_w  = (const float*)d_in[12];
    const float* lin2_b  = (const float*)d_in[13];
    const int* srcp = eidx;
    const int* dstp = eidx + N_EDGES;

    char* ws = (char*)d_ws;
    size_t o = 0;
    int*      bucketCnt    = (int*)(ws + o);   o += (size_t)256 * 4;
    int*      bucketOff    = (int*)(ws + o);   o += (size_t)256 * 4;
    int*      bucketCursor = (int*)(ws + o);   o += (size_t)256 * 4;
    int*      partial      = (int*)(ws + o);   o += (size_t)256 * 4;
    float*    inv          = (float*)(ws + o); o += (size_t)R_REL * N_NODES * 4;
    int*      degv         = (int*)(ws + o);   o += (size_t)N_NODES * 4;
    int*      offv         = (int*)(ws + o);   o += (size_t)N_NODES * 4;
    int*      binned       = (int*)(ws + o);   o += (size_t)N_EDGES * 4;
    int*      elist        = (int*)(ws + o);   o += (size_t)N_EDGES * 4;
    unsigned* g            = (unsigned*)(ws + o); o += (size_t)G_BATCH * H2 * 4;
    float*    h1           = (float*)(ws + o); o += (size_t)N_NODES * H1 * 4;
    float*    out2         = (float*)(ws + o); o += (size_t)N_NODES * H2 * 4;
    // total ~33 MB

    hipMemsetAsync(bucketCnt, 0, 256 * 4, stream);
    hipMemsetAsync(g, 0, (size_t)G_BATCH * H2 * 4, stream);

    bcount_kernel<<<NBIN, 256, 0, stream>>>(dstp, bucketCnt);
    bscan_kernel<<<1, 256, 0, stream>>>(bucketCnt, bucketOff, bucketCursor);
    bin_kernel<<<NBIN, 256, 0, stream>>>(srcp, dstp, etype, bucketCursor, binned);
    bcnt2_kernel<<<BKT, 256, 0, stream>>>(binned, bucketOff, bucketCnt, inv, degv,
                                          partial);
    scanB_kernel<<<1, 256, 0, stream>>>(partial);
    scanC_kernel<<<BKT, 256, 0, stream>>>(degv, partial, offv);
    bscatter_kernel<<<BKT, 256, 0, stream>>>(binned, bucketOff, bucketCnt, offv,
                                             elist);

    layer1_kernel<<<(N_NODES + 7) / 8, 256, 0, stream>>>(
        x, offv, degv, elist, inv, W1_rel, W1_root, b1, h1);
    layer2_kernel<<<(N_NODES + 7) / 8, 256, 0, stream>>>(
        h1, offv, degv, elist, inv, W2_rel, W2_root, b2, out2);

    pool_kernel<<<(N_NODES + POOL_NODES - 1) / POOL_NODES, 64, 0, stream>>>(
        out2, batch, g);
    mlp_kernel<<<1, 256, 0, stream>>>(g, lin1_w, lin1_b, lin2_w, lin2_b,
                                      (float*)d_out);
}

// Round 6
// 320.065 us; speedup vs baseline: 7.1595x; 1.1209x over previous
//
#include <hip/hip_runtime.h>

#define N_NODES 50000
#define N_EDGES 1600000
#define R_REL 4
#define F_IN 32
#define H1 32
#define H2 64
#define NC 3
#define G_BATCH 64
#define BKT 196                        // buckets = ceil(N/256)
#define CHUNK 6400                     // edges per binning block
#define NBIN (N_EDGES / CHUNK)         // 250 exactly
#define ELIST_CAP (N_EDGES + N_NODES * R_REL * 8)   // padded elist upper bound

// ---------------- 0. padded copy of x + zero rows ----------------
__global__ __launch_bounds__(256) void copyx_kernel(const float* __restrict__ x,
                                                    float* __restrict__ xp,
                                                    float* __restrict__ h1zero) {
    int i = blockIdx.x * 256 + threadIdx.x;
    if (i < (N_NODES + 1) * F_IN)
        xp[i] = (i < N_NODES * F_IN) ? x[i] : 0.0f;
    if (i < H1) h1zero[i] = 0.0f;      // h1 row N (sentinel row for layer 2)
}

// ---------------- 1. coarse bucket histogram (bucket = dst>>8) ----------------
__global__ __launch_bounds__(256) void bcount_kernel(const int* __restrict__ dstp,
                                                     int* __restrict__ bucketCnt) {
    __shared__ int h[BKT];
    for (int i = threadIdx.x; i < BKT; i += 256) h[i] = 0;
    __syncthreads();
    int e0 = blockIdx.x * CHUNK;
    for (int e = e0 + threadIdx.x; e < e0 + CHUNK; e += 256)
        atomicAdd(&h[dstp[e] >> 8], 1);
    __syncthreads();
    for (int i = threadIdx.x; i < BKT; i += 256)
        if (h[i]) atomicAdd(&bucketCnt[i], h[i]);
}

// ---------------- 2. exclusive scan of bucket counts ----------------
__global__ __launch_bounds__(256) void bscan_kernel(const int* __restrict__ bucketCnt,
                                                    int* __restrict__ bucketOff,
                                                    int* __restrict__ bucketCursor) {
    __shared__ int s[256];
    int v = (threadIdx.x < BKT) ? bucketCnt[threadIdx.x] : 0;
    s[threadIdx.x] = v;
    __syncthreads();
    for (int w = 1; w < 256; w <<= 1) {
        int t = (threadIdx.x >= w) ? s[threadIdx.x - w] : 0;
        __syncthreads();
        s[threadIdx.x] += t;
        __syncthreads();
    }
    if (threadIdx.x < BKT) {
        int o = s[threadIdx.x] - v;
        bucketOff[threadIdx.x] = o;
        bucketCursor[threadIdx.x] = o;
    }
}

// ---------------- 3. bin edges into bucket-contiguous regions ----------------
// record = src | type<<16 | dstLocal<<18
__global__ __launch_bounds__(256) void bin_kernel(const int* __restrict__ srcp,
                                                  const int* __restrict__ dstp,
                                                  const int* __restrict__ etype,
                                                  int* __restrict__ bucketCursor,
                                                  int* __restrict__ binned) {
    __shared__ int h[BKT];
    __shared__ int lc[BKT];
    for (int i = threadIdx.x; i < BKT; i += 256) { h[i] = 0; lc[i] = 0; }
    __syncthreads();
    int e0 = blockIdx.x * CHUNK;
    for (int e = e0 + threadIdx.x; e < e0 + CHUNK; e += 256)
        atomicAdd(&h[dstp[e] >> 8], 1);
    __syncthreads();
    for (int i = threadIdx.x; i < BKT; i += 256) {
        int c = h[i];
        h[i] = c ? atomicAdd(&bucketCursor[i], c) : 0;
    }
    __syncthreads();
    for (int e = e0 + threadIdx.x; e < e0 + CHUNK; e += 256) {
        int d = dstp[e];
        int b = d >> 8;
        int rank = atomicAdd(&lc[b], 1);
        binned[h[b] + rank] = srcp[e] | (etype[e] << 16) | ((d & 0xFF) << 18);
    }
}

// ---------------- 4. per-(node,rel) counts + inv + padded-degree sums --------
__global__ __launch_bounds__(256) void bcnt2_kernel(const int* __restrict__ binned,
                                                    const int* __restrict__ bucketOff,
                                                    const int* __restrict__ bucketCnt,
                                                    float* __restrict__ inv,
                                                    int* __restrict__ rcnt4,
                                                    int* __restrict__ partial) {
    __shared__ int cnt4[256 * R_REL];
    __shared__ int s[256];
    for (int i = threadIdx.x; i < 256 * R_REL; i += 256) cnt4[i] = 0;
    __syncthreads();
    int b = blockIdx.x;
    int i0 = bucketOff[b], i1 = i0 + bucketCnt[b];
    for (int i = i0 + threadIdx.x; i < i1; i += 256) {
        int p = binned[i];
        atomicAdd(&cnt4[((p >> 18) & 0xFF) * R_REL + ((p >> 16) & 3)], 1);
    }
    __syncthreads();
    int n = b * 256 + threadIdx.x;
    int d = 0;
    if (n < N_NODES) {
        int4 w;
        int c0 = cnt4[threadIdx.x * 4 + 0];
        int c1 = cnt4[threadIdx.x * 4 + 1];
        int c2 = cnt4[threadIdx.x * 4 + 2];
        int c3 = cnt4[threadIdx.x * 4 + 3];
        inv[0 * N_NODES + n] = 1.0f / (float)(c0 > 1 ? c0 : 1);
        inv[1 * N_NODES + n] = 1.0f / (float)(c1 > 1 ? c1 : 1);
        inv[2 * N_NODES + n] = 1.0f / (float)(c2 > 1 ? c2 : 1);
        inv[3 * N_NODES + n] = 1.0f / (float)(c3 > 1 ? c3 : 1);
        w.x = c0; w.y = c1; w.z = c2; w.w = c3;
        *(int4*)&rcnt4[n * 4] = w;
        d = ((c0 + 7) & ~7) + ((c1 + 7) & ~7) + ((c2 + 7) & ~7) + ((c3 + 7) & ~7);
    }
    s[threadIdx.x] = d;
    __syncthreads();
    for (int w = 128; w > 0; w >>= 1) {
        if (threadIdx.x < w) s[threadIdx.x] += s[threadIdx.x + w];
        __syncthreads();
    }
    if (threadIdx.x == 0) partial[b] = s[0];
}

// ---------------- 5. scan of block sums (exclusive), one block ----------------
__global__ __launch_bounds__(256) void scanB_kernel(int* __restrict__ partial) {
    __shared__ int s[256];
    int v = (threadIdx.x < BKT) ? partial[threadIdx.x] : 0;
    s[threadIdx.x] = v;
    __syncthreads();
    for (int w = 1; w < 256; w <<= 1) {
        int t = (threadIdx.x >= w) ? s[threadIdx.x - w] : 0;
        __syncthreads();
        s[threadIdx.x] += t;
        __syncthreads();
    }
    if (threadIdx.x < BKT) partial[threadIdx.x] = s[threadIdx.x] - v;  // exclusive
}

// ---------------- 6. per-(node,rel) padded sub-offsets ----------------
__global__ __launch_bounds__(256) void scanC_kernel(const int* __restrict__ rcnt4,
                                                    const int* __restrict__ partial,
                                                    int* __restrict__ poff4) {
    __shared__ int s[256];
    int n = blockIdx.x * 256 + threadIdx.x;
    int p0 = 0, p1 = 0, p2 = 0, p3 = 0, d = 0;
    if (n < N_NODES) {
        int4 rc = *(const int4*)&rcnt4[n * 4];
        p0 = (rc.x + 7) & ~7;
        p1 = (rc.y + 7) & ~7;
        p2 = (rc.z + 7) & ~7;
        p3 = (rc.w + 7) & ~7;
        d = p0 + p1 + p2 + p3;
    }
    s[threadIdx.x] = d;
    __syncthreads();
    for (int w = 1; w < 256; w <<= 1) {
        int t = (threadIdx.x >= w) ? s[threadIdx.x - w] : 0;
        __syncthreads();
        s[threadIdx.x] += t;
        __syncthreads();
    }
    if (n < N_NODES) {
        int base = partial[blockIdx.x] + s[threadIdx.x] - d;
        int4 w;
        w.x = base;
        w.y = base + p0;
        w.z = base + p0 + p1;
        w.w = base + p0 + p1 + p2;
        *(int4*)&poff4[n * 4] = w;
    }
}

// ---------------- 7. final CSR scatter, rel-sorted + sentinel padding --------
__global__ __launch_bounds__(256) void bscatter_kernel(const int* __restrict__ binned,
                                                       const int* __restrict__ bucketOff,
                                                       const int* __restrict__ bucketCnt,
                                                       const int* __restrict__ poff4,
                                                       const int* __restrict__ rcnt4,
                                                       int* __restrict__ elist) {
    __shared__ int cur[256 * 4];
    int b = blockIdx.x, t = threadIdx.x;
    int n = b * 256 + t;
    int4 po = make_int4(0, 0, 0, 0);
    if (n < N_NODES) po = *(const int4*)&poff4[n * 4];
    cur[t * 4 + 0] = po.x;
    cur[t * 4 + 1] = po.y;
    cur[t * 4 + 2] = po.z;
    cur[t * 4 + 3] = po.w;
    __syncthreads();
    int i0 = bucketOff[b], i1 = i0 + bucketCnt[b];
    for (int i = i0 + t; i < i1; i += 256) {
        int p = binned[i];
        int pos = atomicAdd(&cur[((p >> 18) & 0xFF) * 4 + ((p >> 16) & 3)], 1);
        elist[pos] = p & 0xFFFF;       // src only (rel implied by segment)
    }
    __syncthreads();
    if (n < N_NODES) {
        int4 rc = *(const int4*)&rcnt4[n * 4];
        int rcv[4] = {rc.x, rc.y, rc.z, rc.w};
        int pov[4] = {po.x, po.y, po.z, po.w};
#pragma unroll
        for (int r = 0; r < R_REL; ++r) {
            int e = cur[t * 4 + r];
            int pe = pov[r] + ((rcv[r] + 7) & ~7);
            for (; e < pe; ++e) elist[e] = N_NODES;   // zero-row sentinel
        }
    }
}

// ---------------- 8. layer 1: gather-aggregate + transform, fused ReLU -------
// 8 nodes/block, 32 lanes/node. Rel-sorted padded segments: no masks, no
// type bits — per slot: shfl + addr + load + add.
__global__ __launch_bounds__(256, 8) void layer1_kernel(
    const float* __restrict__ xp, const int* __restrict__ poff4,
    const int* __restrict__ rcnt4, const int* __restrict__ elist,
    const float* __restrict__ inv, const float* __restrict__ W_rel,
    const float* __restrict__ W_root, const float* __restrict__ b,
    float* __restrict__ h1) {
    __shared__ float sxr[8][F_IN];
    __shared__ float sagg[8][R_REL][F_IN];

    int ln = threadIdx.x >> 5, c = threadIdx.x & 31;
    int n = blockIdx.x * 8 + ln;
    if (n >= N_NODES) return;

    sxr[ln][c] = xp[n * F_IN + c];
    int4 po = *(const int4*)&poff4[n * 4];
    int4 rc = *(const int4*)&rcnt4[n * 4];
    int pov[4] = {po.x, po.y, po.z, po.w};
    int rcv[4] = {rc.x, rc.y, rc.z, rc.w};
    int c7 = c & 7;
#pragma unroll
    for (int r = 0; r < R_REL; ++r) {
        int sb = pov[r];
        int pc = (rcv[r] + 7) & ~7;
        float a = 0.0f;
        for (int eb = 0; eb < pc; eb += 8) {
            int pv = elist[sb + eb + c7];
            float v[8];
#pragma unroll
            for (int j = 0; j < 8; ++j) {
                int p = __shfl(pv, j, 8);
                v[j] = xp[p * F_IN + c];
            }
#pragma unroll
            for (int j = 0; j < 8; ++j) a += v[j];
        }
        sagg[ln][r][c] = a * inv[r * N_NODES + n];
    }

    float o = b[c];
#pragma unroll
    for (int i = 0; i < F_IN; ++i)
        o = fmaf(sxr[ln][i], W_root[i * H1 + c], o);
#pragma unroll
    for (int r = 0; r < R_REL; ++r)
#pragma unroll
        for (int i = 0; i < F_IN; ++i)
            o = fmaf(sagg[ln][r][i], W_rel[r * F_IN * H1 + i * H1 + c], o);
    h1[n * H1 + c] = fmaxf(o, 0.0f);
}

// ---------------- 9. layer 2: same, F_out=64 ----------------
__global__ __launch_bounds__(256, 8) void layer2_kernel(
    const float* __restrict__ h1, const int* __restrict__ poff4,
    const int* __restrict__ rcnt4, const int* __restrict__ elist,
    const float* __restrict__ inv, const float* __restrict__ W_rel,
    const float* __restrict__ W_root, const float* __restrict__ b,
    float* __restrict__ out2) {
    __shared__ float sxr[8][H1];
    __shared__ float sagg[8][R_REL][H1];

    int ln = threadIdx.x >> 5, c = threadIdx.x & 31;
    int n = blockIdx.x * 8 + ln;
    if (n >= N_NODES) return;

    sxr[ln][c] = h1[n * H1 + c];
    int4 po = *(const int4*)&poff4[n * 4];
    int4 rc = *(const int4*)&rcnt4[n * 4];
    int pov[4] = {po.x, po.y, po.z, po.w};
    int rcv[4] = {rc.x, rc.y, rc.z, rc.w};
    int c7 = c & 7;
#pragma unroll
    for (int r = 0; r < R_REL; ++r) {
        int sb = pov[r];
        int pc = (rcv[r] + 7) & ~7;
        float a = 0.0f;
        for (int eb = 0; eb < pc; eb += 8) {
            int pv = elist[sb + eb + c7];
            float v[8];
#pragma unroll
            for (int j = 0; j < 8; ++j) {
                int p = __shfl(pv, j, 8);
                v[j] = h1[p * H1 + c];
            }
#pragma unroll
            for (int j = 0; j < 8; ++j) a += v[j];
        }
        sagg[ln][r][c] = a * inv[r * N_NODES + n];
    }

    float o0 = b[c], o1 = b[c + 32];
#pragma unroll
    for (int i = 0; i < H1; ++i) {
        float xv = sxr[ln][i];
        o0 = fmaf(xv, W_root[i * H2 + c], o0);
        o1 = fmaf(xv, W_root[i * H2 + c + 32], o1);
    }
#pragma unroll
    for (int r = 0; r < R_REL; ++r)
#pragma unroll
        for (int i = 0; i < H1; ++i) {
            float av = sagg[ln][r][i];
            o0 = fmaf(av, W_rel[r * H1 * H2 + i * H2 + c], o0);
            o1 = fmaf(av, W_rel[r * H1 * H2 + i * H2 + c + 32], o1);
        }
    out2[n * H2 + c] = o0;
    out2[n * H2 + c + 32] = o1;
}

// ---------------- 10. pooling: relu + segment max ----------------
#define POOL_NODES 32
__global__ __launch_bounds__(64) void pool_kernel(
    const float* __restrict__ out2, const int* __restrict__ batch,
    unsigned int* __restrict__ g) {
    int col = threadIdx.x;
    int n0 = blockIdx.x * POOL_NODES;
    if (n0 >= N_NODES) return;
    int n1 = n0 + POOL_NODES;
    if (n1 > N_NODES) n1 = N_NODES;
    int cur = batch[n0];
    float m = 0.0f;
    for (int n = n0; n < n1; ++n) {
        int bnow = batch[n];
        if (bnow != cur) {
            atomicMax(&g[cur * H2 + col], __float_as_uint(m));
            cur = bnow;
            m = 0.0f;
        }
        m = fmaxf(m, out2[n * H2 + col]);
    }
    atomicMax(&g[cur * H2 + col], __float_as_uint(m));
}

// ---------------- 11. MLP head ----------------
__global__ __launch_bounds__(256) void mlp_kernel(
    const unsigned int* __restrict__ gbits, const float* __restrict__ lin1_w,
    const float* __restrict__ lin1_b, const float* __restrict__ lin2_w,
    const float* __restrict__ lin2_b, float* __restrict__ out) {
    __shared__ float sg[G_BATCH][H2];
    __shared__ float sh[G_BATCH][H1];
    __shared__ float sw1[H2 * H1];
    for (int i = threadIdx.x; i < G_BATCH * H2; i += 256)
        sg[i / H2][i % H2] = __uint_as_float(gbits[i]);
    for (int i = threadIdx.x; i < H2 * H1; i += 256) sw1[i] = lin1_w[i];
    __syncthreads();
    for (int i = threadIdx.x; i < G_BATCH * H1; i += 256) {
        int gi = i / H1, c = i % H1;
        float a = lin1_b[c];
#pragma unroll
        for (int k = 0; k < H2; ++k) a = fmaf(sg[gi][k], sw1[k * H1 + c], a);
        sh[gi][c] = fmaxf(a, 0.0f);
    }
    __syncthreads();
    for (int i = threadIdx.x; i < G_BATCH * NC; i += 256) {
        int gi = i / NC, c = i % NC;
        float a = lin2_b[c];
#pragma unroll
        for (int k = 0; k < H1; ++k) a = fmaf(sh[gi][k], lin2_w[k * NC + c], a);
        out[gi * NC + c] = a;
    }
}

// ---------------- launch ----------------
extern "C" void kernel_launch(void* const* d_in, const int* in_sizes, int n_in,
                              void* d_out, int out_size, void* d_ws, size_t ws_size,
                              hipStream_t stream) {
    const float* x       = (const float*)d_in[0];
    const int*   eidx    = (const int*)d_in[1];
    const int*   etype   = (const int*)d_in[2];
    const int*   batch   = (const int*)d_in[3];
    const float* W1_rel  = (const float*)d_in[4];
    const float* W1_root = (const float*)d_in[5];
    const float* b1      = (const float*)d_in[6];
    const float* W2_rel  = (const float*)d_in[7];
    const float* W2_root = (const float*)d_in[8];
    const float* b2      = (const float*)d_in[9];
    const float* lin1_w  = (const float*)d_in[10];
    const float* lin1_b  = (const float*)d_in[11];
    const float* lin2_w  = (const float*)d_in[12];
    const float* lin2_b  = (const float*)d_in[13];
    const int* srcp = eidx;
    const int* dstp = eidx + N_EDGES;

    char* ws = (char*)d_ws;
    size_t o = 0;
    int*      bucketCnt    = (int*)(ws + o);   o += (size_t)256 * 4;
    int*      bucketOff    = (int*)(ws + o);   o += (size_t)256 * 4;
    int*      bucketCursor = (int*)(ws + o);   o += (size_t)256 * 4;
    int*      partial      = (int*)(ws + o);   o += (size_t)256 * 4;
    float*    inv          = (float*)(ws + o); o += (size_t)R_REL * N_NODES * 4;
    int*      rcnt4        = (int*)(ws + o);   o += (size_t)R_REL * N_NODES * 4;
    int*      poff4        = (int*)(ws + o);   o += (size_t)R_REL * N_NODES * 4;
    int*      binned       = (int*)(ws + o);   o += (size_t)N_EDGES * 4;
    int*      elist        = (int*)(ws + o);   o += (size_t)ELIST_CAP * 4;
    unsigned* g            = (unsigned*)(ws + o); o += (size_t)G_BATCH * H2 * 4;
    float*    xp           = (float*)(ws + o); o += (size_t)(N_NODES + 1) * F_IN * 4;
    float*    h1           = (float*)(ws + o); o += (size_t)(N_NODES + 1) * H1 * 4;
    float*    out2         = (float*)(ws + o); o += (size_t)N_NODES * H2 * 4;
    // total ~48 MB

    hipMemsetAsync(bucketCnt, 0, 256 * 4, stream);
    hipMemsetAsync(g, 0, (size_t)G_BATCH * H2 * 4, stream);

    copyx_kernel<<<((N_NODES + 1) * F_IN + 255) / 256, 256, 0, stream>>>(
        x, xp, h1 + (size_t)N_NODES * H1);
    bcount_kernel<<<NBIN, 256, 0, stream>>>(dstp, bucketCnt);
    bscan_kernel<<<1, 256, 0, stream>>>(bucketCnt, bucketOff, bucketCursor);
    bin_kernel<<<NBIN, 256, 0, stream>>>(srcp, dstp, etype, bucketCursor, binned);
    bcnt2_kernel<<<BKT, 256, 0, stream>>>(binned, bucketOff, bucketCnt, inv,
                                          rcnt4, partial);
    scanB_kernel<<<1, 256, 0, stream>>>(partial);
    scanC_kernel<<<BKT, 256, 0, stream>>>(rcnt4, partial, poff4);
    bscatter_kernel<<<BKT, 256, 0, stream>>>(binned, bucketOff, bucketCnt, poff4,
                                             rcnt4, elist);

    layer1_kernel<<<(N_NODES + 7) / 8, 256, 0, stream>>>(
        xp, poff4, rcnt4, elist, inv, W1_rel, W1_root, b1, h1);
    layer2_kernel<<<(N_NODES + 7) / 8, 256, 0, stream>>>(
        h1, poff4, rcnt4, elist, inv, W2_rel, W2_root, b2, out2);

    pool_kernel<<<(N_NODES + POOL_NODES - 1) / POOL_NODES, 64, 0, stream>>>(
        out2, batch, g);
    mlp_kernel<<<1, 256, 0, stream>>>(g, lin1_w, lin1_b, lin2_w, lin2_b,
                                      (float*)d_out);
}